// Round 1
// baseline (15295.226 us; speedup 1.0000x reference)
//
#include <hip/hip_runtime.h>
#include <math.h>

#ifndef M_PI
#define M_PI 3.14159265358979323846
#endif

#define NXx   360
#define NXY   (NXx*NXx)
#define NTRc  32
#define NMEASc 256
#define NSTEPSc 640
#define NBCc  15
#define PADc  73
#define NVc   214

// f32 constants rounded from the exact double values used by the reference
#define C2f   1.3333334f        // 4/3
#define C3f  (-0.083333336f)    // -1/12
#define ADX2  0.11111111f       // (0.2/0.6)^2 rounded to f32
#define DT2f  0.04f             // DT*DT
#define DTf   0.2f
#define DXf   0.6f

__global__ void velmin_kernel(const float* __restrict__ v, float* __restrict__ velmin) {
    __shared__ float s[256];
    float m = 1.5f;  // pad value participates in the min over the padded array
    for (int i = threadIdx.x; i < NVc*NVc; i += 256) m = fminf(m, v[i]);
    s[threadIdx.x] = m;
    __syncthreads();
    for (int o = 128; o > 0; o >>= 1) {
        if (threadIdx.x < o) s[threadIdx.x] = fminf(s[threadIdx.x], s[threadIdx.x+o]);
        __syncthreads();
    }
    if (threadIdx.x == 0) *velmin = s[0];
}

__global__ void coef_kernel(const float* __restrict__ v, const float* __restrict__ velmin_p,
                            float* __restrict__ alpha, float* __restrict__ t1,
                            float* __restrict__ t0) {
    int idx = blockIdx.x*256 + threadIdx.x;
    if (idx >= NXY) return;
    int i = idx / NXx, j = idx - i*NXx;
    float vc = 1.5f;
    if (i >= PADc && i < PADc+NVc && j >= PADc && j < PADc+NVc)
        vc = v[(i-PADc)*NVc + (j-PADc)];
    float v2 = vc*vc;
    float al = v2 * ADX2;
    float velmin = *velmin_p;
    const float a = (float)((NBCc-1)*0.6);                 // 8.4
    float ks = 3.0f*velmin*9.2103405f/(2.0f*a);            // log(1e4) as f32
    // damping profile; .at[].set order => columns overwrite rows (last write wins)
    float damp = 0.0f;
    int k = -1;
    if (j >= NXx-NBCc)      k = j-(NXx-NBCc);
    else if (j < NBCc)      k = NBCc-1-j;
    else if (i >= NXx-NBCc) k = i-(NXx-NBCc);
    else if (i < NBCc)      k = NBCc-1-i;
    if (k >= 0) { float r = (float)k*DXf/a; damp = ks*r*r; }
    float kap = damp*DTf;
    alpha[idx] = al;
    t1[idx] = 2.0f + 2.0f*(-2.5f)*al - kap;
    t0[idx] = 1.0f - kap;
}

__global__ void beta_kernel(const float* __restrict__ v, const int* __restrict__ in_inds,
                            float* __restrict__ beta) {
    int tr = threadIdx.x;
    if (tr >= NTRc) return;
    int idx = in_inds[tr];
    int i = idx / NXx, j = idx - i*NXx;
    float vc = 1.5f;
    if (i >= PADc && i < PADc+NVc && j >= PADc && j < PADc+NVc)
        vc = v[(i-PADc)*NVc + (j-PADc)];
    beta[tr] = DT2f*vc*vc;
}

__global__ __launch_bounds__(256) void step_kernel(
    const float* __restrict__ pprev,   // p0 (read pointwise; same buffer as pnext)
    const float* __restrict__ pcur,    // p1 (stencil source; also last step's pf)
    float* __restrict__ pnext,         // output buffer (aliases pprev — safe, pointwise)
    const float* __restrict__ alpha, const float* __restrict__ t1,
    const float* __restrict__ t0,
    const float* __restrict__ beta, const float* __restrict__ src,
    const int* __restrict__ in_inds, const int* __restrict__ meas_inds,
    float* __restrict__ out, int t)
{
    int tr  = blockIdx.y;
    // fold previous step's measurement gather into this launch (pcur is stable here)
    if (t > 0 && blockIdx.x == 0) {
        int m = threadIdx.x;  // blockDim.x == NMEASc == 256
        out[((size_t)tr*NSTEPSc + (t-1))*NMEASc + m] =
            pcur[(size_t)tr*NXY + meas_inds[m]];
    }
    int rem = blockIdx.x*256 + threadIdx.x;
    if (rem >= NXY) return;
    int i = rem / NXx, j = rem - i*NXx;
    const float* pc = pcur + (size_t)tr*NXY;

    int im1 = (i==0)      ? NXx-1    : i-1;
    int ip1 = (i==NXx-1)  ? 0        : i+1;
    int im2 = (i<2)       ? i+NXx-2  : i-2;
    int ip2 = (i>=NXx-2)  ? i-(NXx-2): i+2;
    int jm1 = (j==0)      ? NXx-1    : j-1;
    int jp1 = (j==NXx-1)  ? 0        : j+1;
    int jm2 = (j<2)       ? j+NXx-2  : j-2;
    int jp2 = (j>=NXx-2)  ? j-(NXx-2): j+2;

    float lap = C2f*(pc[im1*NXx+j] + pc[ip1*NXx+j] + pc[i*NXx+jm1] + pc[i*NXx+jp1])
              + C3f*(pc[im2*NXx+j] + pc[ip2*NXx+j] + pc[i*NXx+jm2] + pc[i*NXx+jp2]);

    float p = alpha[rem]*lap + t1[rem]*pc[rem] - t0[rem]*pprev[(size_t)tr*NXY + rem];
    if (rem == in_inds[tr]) p += beta[tr]*src[t];
    pnext[(size_t)tr*NXY + rem] = p;
}

__global__ void gather_kernel(const float* __restrict__ pcur,
                              const int* __restrict__ meas_inds,
                              float* __restrict__ out, int t) {
    int tr = blockIdx.x, m = threadIdx.x;
    out[((size_t)tr*NSTEPSc + t)*NMEASc + m] = pcur[(size_t)tr*NXY + meas_inds[m]];
}

extern "C" void kernel_launch(void* const* d_in, const int* in_sizes, int n_in,
                              void* d_out, int out_size, void* d_ws, size_t ws_size,
                              hipStream_t stream) {
    const float* v = (const float*)d_in[0];
    float* out = (float*)d_out;

    // workspace layout
    float* pA    = (float*)d_ws;                 // NTR*NXY
    float* pB    = pA + (size_t)NTRc*NXY;        // NTR*NXY
    float* alpha = pB + (size_t)NTRc*NXY;        // NXY
    float* t1    = alpha + NXY;                  // NXY
    float* t0    = t1 + NXY;                     // NXY
    float* beta  = t0 + NXY;                     // NTR
    float* velmin= beta + NTRc;                  // 1
    float* src_d = velmin + 1;                   // NSTEPS
    int*   meas_d= (int*)(src_d + NSTEPSc);      // NMEAS
    int*   in_d  = meas_d + NMEASc;              // NTR

    // host-side tables: double precision (glibc libm == numpy float64 path)
    static int   h_tab[NMEASc + NTRc];
    static float h_src[NSTEPSc];
    {
        const double step = 2.0*M_PI/256.0;      // exact /256 — matches linspace
        for (int k = 0; k < NMEASc; ++k) {
            double th = (double)k * step;
            int ti0 = (int)floor(160.0*cos(th) + 179.5);
            int ti1 = (int)floor(160.0*sin(th) + 179.5);
            h_tab[k] = NXx*ti0 + ti1;
        }
        for (int r = 0; r < NTRc; ++r) h_tab[NMEASc + r] = h_tab[r*(NMEASc/NTRc)];
        for (int t = 0; t < NSTEPSc; ++t) {
            double tt = (double)t * 0.2;
            double d  = tt - 3.2;
            double e  = exp(-(d*d) / 288.0);     // 2*SIGMA^2 = 288
            double s  = sin(6.283185307179586 * tt);
            h_src[t] = (float)(e * s);
        }
    }
    hipMemcpyAsync(meas_d, h_tab, sizeof(int)*(NMEASc+NTRc), hipMemcpyHostToDevice, stream);
    hipMemcpyAsync(src_d, h_src, sizeof(float)*NSTEPSc, hipMemcpyHostToDevice, stream);
    hipMemsetAsync(pA, 0, sizeof(float)*(size_t)NTRc*NXY*2, stream);

    velmin_kernel<<<1, 256, 0, stream>>>(v, velmin);
    coef_kernel<<<(NXY+255)/256, 256, 0, stream>>>(v, velmin, alpha, t1, t0);
    beta_kernel<<<1, 64, 0, stream>>>(v, in_d, beta);

    const int gx = (NXY + 255)/256;  // 507
    const float* p0 = pA;
    const float* p1 = pB;
    for (int t = 0; t < NSTEPSc; ++t) {
        step_kernel<<<dim3(gx, NTRc), 256, 0, stream>>>(
            p0, p1, (float*)p0, alpha, t1, t0, beta, src_d, in_d, meas_d, out, t);
        const float* tmp = p0; p0 = p1; p1 = tmp;   // p1 now holds the newest field
    }
    gather_kernel<<<NTRc, NMEASc, 0, stream>>>(p1, meas_d, out, NSTEPSc-1);
}

// Round 2
// 7993.710 us; speedup vs baseline: 1.9134x; 1.9134x over previous
//
#include <hip/hip_runtime.h>
#include <math.h>

#ifndef M_PI
#define M_PI 3.14159265358979323846
#endif

#define NXx   360
#define NXY   (NXx*NXx)
#define NTRc  32
#define NMEASc 256
#define NSTEPSc 640
#define NBCc  15
#define PADc  73
#define NVc   214
#define NG    (NXx/4)          // 90 float4-groups per row
#define NGRP  (NXx*NG)         // 32400 groups per trace

#define C2f   1.3333334f        // 4/3
#define C3f  (-0.083333336f)    // -1/12
#define ADX2  0.11111111f       // (0.2/0.6)^2 rounded to f32
#define DT2f  0.04f
#define DTf   0.2f
#define DXf   0.6f

__global__ void velmin_kernel(const float* __restrict__ v, float* __restrict__ velmin) {
    __shared__ float s[256];
    float m = 1.5f;  // pad value participates in the min
    for (int i = threadIdx.x; i < NVc*NVc; i += 256) m = fminf(m, v[i]);
    s[threadIdx.x] = m;
    __syncthreads();
    for (int o = 128; o > 0; o >>= 1) {
        if (threadIdx.x < o) s[threadIdx.x] = fminf(s[threadIdx.x], s[threadIdx.x+o]);
        __syncthreads();
    }
    if (threadIdx.x == 0) *velmin = s[0];
}

// writes alpha[] and kap[] (t1/t0 recomputed in the step kernel with identical arithmetic)
__global__ void coef_kernel(const float* __restrict__ v, const float* __restrict__ velmin_p,
                            float* __restrict__ alpha, float* __restrict__ kap) {
    int idx = blockIdx.x*256 + threadIdx.x;
    if (idx >= NXY) return;
    int i = idx / NXx, j = idx - i*NXx;
    float vc = 1.5f;
    if (i >= PADc && i < PADc+NVc && j >= PADc && j < PADc+NVc)
        vc = v[(i-PADc)*NVc + (j-PADc)];
    float v2 = vc*vc;
    float al = v2 * ADX2;
    float velmin = *velmin_p;
    const float a = (float)((NBCc-1)*0.6);                 // 8.4
    float ks = 3.0f*velmin*9.2103405f/(2.0f*a);            // log(1e4) as f32
    // damping profile; .at[].set order => columns overwrite rows (last write wins)
    float damp = 0.0f;
    int k = -1;
    if (j >= NXx-NBCc)      k = j-(NXx-NBCc);
    else if (j < NBCc)      k = NBCc-1-j;
    else if (i >= NXx-NBCc) k = i-(NXx-NBCc);
    else if (i < NBCc)      k = NBCc-1-i;
    if (k >= 0) { float r = (float)k*DXf/a; damp = ks*r*r; }
    alpha[idx] = al;
    kap[idx]   = damp*DTf;
}

__global__ void beta_kernel(const float* __restrict__ v, const int* __restrict__ in_inds,
                            float* __restrict__ beta) {
    int tr = threadIdx.x;
    if (tr >= NTRc) return;
    int idx = in_inds[tr];
    int i = idx / NXx, j = idx - i*NXx;
    float vc = 1.5f;
    if (i >= PADc && i < PADc+NVc && j >= PADc && j < PADc+NVc)
        vc = v[(i-PADc)*NVc + (j-PADc)];
    beta[tr] = DT2f*vc*vc;
}

// One thread = 4 consecutive j-cells (one float4). All loads/stores are aligned 16B.
__global__ __launch_bounds__(256) void step_kernel(
    const float* __restrict__ pprev, const float* __restrict__ pcur,
    float* __restrict__ pnext,
    const float* __restrict__ alpha, const float* __restrict__ kap,
    const float* __restrict__ beta, const float* __restrict__ src,
    const int* __restrict__ in_inds, const int* __restrict__ meas_inds,
    float* __restrict__ out, int t)
{
    int tr = blockIdx.y;
    // fold previous step's measurement gather into this launch (pcur is stable here)
    if (t > 0 && blockIdx.x == 0) {
        int m = threadIdx.x;   // 256 threads == NMEAS
        out[((size_t)tr*NSTEPSc + (t-1))*NMEASc + m] =
            pcur[(size_t)tr*NXY + meas_inds[m]];
    }
    int g = blockIdx.x*256 + threadIdx.x;
    if (g >= NGRP) return;
    int i  = g / NG;
    int jg = g - i*NG;
    int j0 = jg*4;

    const float* pc = pcur + (size_t)tr*NXY;
    int im1 = (i==0)      ? NXx-1     : i-1;
    int ip1 = (i==NXx-1)  ? 0         : i+1;
    int im2 = (i<2)       ? i+NXx-2   : i-2;
    int ip2 = (i>=NXx-2)  ? i-(NXx-2) : i+2;
    int jgm = (jg==0)     ? NG-1      : jg-1;   // wrapped left group (aligned)
    int jgp = (jg==NG-1)  ? 0         : jg+1;   // wrapped right group (aligned)

    const int rowi = i*NXx;
    float4 Cv = *(const float4*)(pc + rowi + j0);
    float4 Lv = *(const float4*)(pc + rowi + jgm*4);
    float4 Rv = *(const float4*)(pc + rowi + jgp*4);
    float4 U1 = *(const float4*)(pc + im1*NXx + j0);
    float4 D1 = *(const float4*)(pc + ip1*NXx + j0);
    float4 U2 = *(const float4*)(pc + im2*NXx + j0);
    float4 D2 = *(const float4*)(pc + ip2*NXx + j0);
    float4 Pp = *(const float4*)(pprev + (size_t)tr*NXY + rowi + j0);
    float4 Al = *(const float4*)(alpha + rowi + j0);
    float4 Kp = *(const float4*)(kap   + rowi + j0);

    float4 pout;
    {   // cell 0: jm1=L.w jp1=C.y jm2=L.z jp2=C.z
        float lap = C2f*(U1.x + D1.x + Lv.w + Cv.y) + C3f*(U2.x + D2.x + Lv.z + Cv.z);
        float t1v = 2.0f + 2.0f*(-2.5f)*Al.x - Kp.x;
        float t0v = 1.0f - Kp.x;
        pout.x = Al.x*lap + t1v*Cv.x - t0v*Pp.x;
    }
    {   // cell 1: jm1=C.x jp1=C.z jm2=L.w jp2=C.w
        float lap = C2f*(U1.y + D1.y + Cv.x + Cv.z) + C3f*(U2.y + D2.y + Lv.w + Cv.w);
        float t1v = 2.0f + 2.0f*(-2.5f)*Al.y - Kp.y;
        float t0v = 1.0f - Kp.y;
        pout.y = Al.y*lap + t1v*Cv.y - t0v*Pp.y;
    }
    {   // cell 2: jm1=C.y jp1=C.w jm2=C.x jp2=R.x
        float lap = C2f*(U1.z + D1.z + Cv.y + Cv.w) + C3f*(U2.z + D2.z + Cv.x + Rv.x);
        float t1v = 2.0f + 2.0f*(-2.5f)*Al.z - Kp.z;
        float t0v = 1.0f - Kp.z;
        pout.z = Al.z*lap + t1v*Cv.z - t0v*Pp.z;
    }
    {   // cell 3: jm1=C.z jp1=R.x jm2=C.y jp2=R.y
        float lap = C2f*(U1.w + D1.w + Cv.z + Rv.x) + C3f*(U2.w + D2.w + Cv.y + Rv.y);
        float t1v = 2.0f + 2.0f*(-2.5f)*Al.w - Kp.w;
        float t0v = 1.0f - Kp.w;
        pout.w = Al.w*lap + t1v*Cv.w - t0v*Pp.w;
    }

    // point-source injection (at most one thread per trace takes this)
    int s = in_inds[tr];
    int d = s - (rowi + j0);
    if (d >= 0 && d < 4) {
        float add = beta[tr]*src[t];
        if      (d==0) pout.x += add;
        else if (d==1) pout.y += add;
        else if (d==2) pout.z += add;
        else           pout.w += add;
    }
    *(float4*)(pnext + (size_t)tr*NXY + rowi + j0) = pout;
}

__global__ void gather_kernel(const float* __restrict__ pcur,
                              const int* __restrict__ meas_inds,
                              float* __restrict__ out, int t) {
    int tr = blockIdx.x, m = threadIdx.x;
    out[((size_t)tr*NSTEPSc + t)*NMEASc + m] = pcur[(size_t)tr*NXY + meas_inds[m]];
}

extern "C" void kernel_launch(void* const* d_in, const int* in_sizes, int n_in,
                              void* d_out, int out_size, void* d_ws, size_t ws_size,
                              hipStream_t stream) {
    const float* v = (const float*)d_in[0];
    float* out = (float*)d_out;

    // workspace layout
    float* pA    = (float*)d_ws;                 // NTR*NXY
    float* pB    = pA + (size_t)NTRc*NXY;        // NTR*NXY
    float* alpha = pB + (size_t)NTRc*NXY;        // NXY
    float* kap   = alpha + NXY;                  // NXY
    float* beta  = kap + NXY;                    // NTR
    float* velmin= beta + NTRc;                  // 1
    float* src_d = velmin + 1;                   // NSTEPS
    int*   meas_d= (int*)(src_d + NSTEPSc);      // NMEAS
    int*   in_d  = meas_d + NMEASc;              // NTR

    // host-side tables in double precision (glibc libm == numpy float64 path)
    static int   h_tab[NMEASc + NTRc];
    static float h_src[NSTEPSc];
    {
        const double step = 2.0*M_PI/256.0;
        for (int k = 0; k < NMEASc; ++k) {
            double th = (double)k * step;
            int ti0 = (int)floor(160.0*cos(th) + 179.5);
            int ti1 = (int)floor(160.0*sin(th) + 179.5);
            h_tab[k] = NXx*ti0 + ti1;
        }
        for (int r = 0; r < NTRc; ++r) h_tab[NMEASc + r] = h_tab[r*(NMEASc/NTRc)];
        for (int t = 0; t < NSTEPSc; ++t) {
            double tt = (double)t * 0.2;
            double d  = tt - 3.2;
            double e  = exp(-(d*d) / 288.0);     // 2*SIGMA^2
            double s  = sin(6.283185307179586 * tt);
            h_src[t] = (float)(e * s);
        }
    }
    hipMemcpyAsync(meas_d, h_tab, sizeof(int)*(NMEASc+NTRc), hipMemcpyHostToDevice, stream);
    hipMemcpyAsync(src_d, h_src, sizeof(float)*NSTEPSc, hipMemcpyHostToDevice, stream);
    hipMemsetAsync(pA, 0, sizeof(float)*(size_t)NTRc*NXY*2, stream);

    velmin_kernel<<<1, 256, 0, stream>>>(v, velmin);
    coef_kernel<<<(NXY+255)/256, 256, 0, stream>>>(v, velmin, alpha, kap);
    beta_kernel<<<1, 64, 0, stream>>>(v, in_d, beta);

    const int gx = (NGRP + 255)/256;   // 127
    const float* p0 = pA;
    const float* p1 = pB;
    for (int t = 0; t < NSTEPSc; ++t) {
        step_kernel<<<dim3(gx, NTRc), 256, 0, stream>>>(
            p0, p1, (float*)p0, alpha, kap, beta, src_d, in_d, meas_d, out, t);
        const float* tmp = p0; p0 = p1; p1 = tmp;
    }
    gather_kernel<<<NTRc, NMEASc, 0, stream>>>(p1, meas_d, out, NSTEPSc-1);
}

// Round 3
// 7849.142 us; speedup vs baseline: 1.9486x; 1.0184x over previous
//
#include <hip/hip_runtime.h>
#include <math.h>

#ifndef M_PI
#define M_PI 3.14159265358979323846
#endif

#define NXx   360
#define NXY   (NXx*NXx)
#define NTRc  32
#define NMEASc 256
#define NSTEPSc 640
#define NBCc  15
#define PADc  73
#define NVc   214

#define BROWS 45               // rows per band
#define NBANDS 8               // bands per trace
#define NBLK  (NTRc*NBANDS)    // 256 blocks == 256 CUs
#define NTHREADS 1024
#define NGrow (NXx/4)          // 90 float4 groups per row
#define GPB   (BROWS*NGrow)    // 4050 groups per band
#define LDSROWS 49             // 2 halo + 45 own + 2 halo
#define LDSFLOATS (2*LDSROWS*NXx)
#define HALO_PER (2*4*NXx)     // per block: 2 slots x 4 rows x 360

#define C2f   1.3333334f
#define C3f  (-0.083333336f)
#define ADX2  0.11111111f
#define DT2f  0.04f
#define DTf   0.2f
#define DXf   0.6f

__global__ void velmin_kernel(const float* __restrict__ v, float* __restrict__ velmin) {
    __shared__ float s[256];
    float m = 1.5f;
    for (int i = threadIdx.x; i < NVc*NVc; i += 256) m = fminf(m, v[i]);
    s[threadIdx.x] = m;
    __syncthreads();
    for (int o = 128; o > 0; o >>= 1) {
        if (threadIdx.x < o) s[threadIdx.x] = fminf(s[threadIdx.x], s[threadIdx.x+o]);
        __syncthreads();
    }
    if (threadIdx.x == 0) *velmin = s[0];
}

__global__ void coef_kernel(const float* __restrict__ v, const float* __restrict__ velmin_p,
                            float* __restrict__ alpha, float* __restrict__ kap) {
    int idx = blockIdx.x*256 + threadIdx.x;
    if (idx >= NXY) return;
    int i = idx / NXx, j = idx - i*NXx;
    float vc = 1.5f;
    if (i >= PADc && i < PADc+NVc && j >= PADc && j < PADc+NVc)
        vc = v[(i-PADc)*NVc + (j-PADc)];
    float v2 = vc*vc;
    float al = v2 * ADX2;
    float velmin = *velmin_p;
    const float a = (float)((NBCc-1)*0.6);
    float ks = 3.0f*velmin*9.2103405f/(2.0f*a);
    float damp = 0.0f;
    int k = -1;
    if (j >= NXx-NBCc)      k = j-(NXx-NBCc);
    else if (j < NBCc)      k = NBCc-1-j;
    else if (i >= NXx-NBCc) k = i-(NXx-NBCc);
    else if (i < NBCc)      k = NBCc-1-i;
    if (k >= 0) { float r = (float)k*DXf/a; damp = ks*r*r; }
    alpha[idx] = al;
    kap[idx]   = damp*DTf;
}

__global__ void beta_kernel(const float* __restrict__ v, const int* __restrict__ in_inds,
                            float* __restrict__ beta) {
    int tr = threadIdx.x;
    if (tr >= NTRc) return;
    int idx = in_inds[tr];
    int i = idx / NXx, j = idx - i*NXx;
    float vc = 1.5f;
    if (i >= PADc && i < PADc+NVc && j >= PADc && j < PADc+NVc)
        vc = v[(i-PADc)*NVc + (j-PADc)];
    beta[tr] = DT2f*vc*vc;
}

// Persistent LDS-resident wavefield kernel. One block per CU; block (tr,band)
// owns rows [band*45, band*45+45) of trace tr. Fields live in LDS for all 640
// steps; only 4 halo rows/step cross blocks (agent-scope = cross-XCD safe).
__global__ __launch_bounds__(NTHREADS, 4) void persist_kernel(
    const float* __restrict__ alpha, const float* __restrict__ kap,
    const float* __restrict__ beta, const float* __restrict__ src,
    const int* __restrict__ meas_inds, const int* __restrict__ in_inds,
    int* flags, float* haloG, float* __restrict__ out)
{
    extern __shared__ float lds[];
    const int tid  = threadIdx.x;
    const int b    = blockIdx.x;
    const int tr   = b >> 3, band = b & 7;
    const int band0 = band*BROWS;
    const int up = (tr<<3) | ((band+7)&7);
    const int dn = (tr<<3) | ((band+1)&7);

    float* buf0 = lds;
    float* buf1 = lds + LDSROWS*NXx;

    for (int i = tid; i < LDSFLOATS; i += NTHREADS) lds[i] = 0.0f;

    // per-thread coefficient registers (4 groups, strided by 1024)
    float4 A0 = make_float4(0,0,0,0), A1=A0, A2=A0, A3=A0, K0=A0, K1=A0, K2=A0, K3=A0;
    {
        int gg;
        gg = tid;        { int r=gg/NGrow, jg=gg-r*NGrow; int gi=(band0+r)*NXx+jg*4;
                           A0=*(const float4*)(alpha+gi); K0=*(const float4*)(kap+gi); }
        gg = tid+1024;   { int r=gg/NGrow, jg=gg-r*NGrow; int gi=(band0+r)*NXx+jg*4;
                           A1=*(const float4*)(alpha+gi); K1=*(const float4*)(kap+gi); }
        gg = tid+2048;   { int r=gg/NGrow, jg=gg-r*NGrow; int gi=(band0+r)*NXx+jg*4;
                           A2=*(const float4*)(alpha+gi); K2=*(const float4*)(kap+gi); }
        gg = tid+3072;   if (gg < GPB) { int r=gg/NGrow, jg=gg-r*NGrow; int gi=(band0+r)*NXx+jg*4;
                           A3=*(const float4*)(alpha+gi); K3=*(const float4*)(kap+gi); }
    }
    const float betaV = beta[tr];
    const int sCell = in_inds[tr];
    const int sr = sCell/NXx, sc = sCell - sr*NXx;
    int srcGG = -1, srcC = 0;
    if (sr >= band0 && sr < band0+BROWS) { srcGG = (sr-band0)*NGrow + (sc>>2); srcC = sc&3; }

    bool mOwn = false; int mOff = 0;
    float* outP = out + ((size_t)tr*NSTEPSc)*NMEASc + tid;
    if (tid < NMEASc) {
        int mi = meas_inds[tid]; int row = mi/NXx, col = mi - row*NXx;
        if (row >= band0 && row < band0+BROWS) { mOwn = true; mOff = (row-band0+2)*NXx + col; }
    }

    float* myHalo = haloG + (size_t)b*HALO_PER;
    float* upHalo = haloG + (size_t)up*HALO_PER;
    float* dnHalo = haloG + (size_t)dn*HALO_PER;

    __syncthreads();

    for (int t = 0; t < NSTEPSc; ++t) {
        const int slot = t & 1, nslot = slot ^ 1;
        float* cur = (slot == 0) ? buf0 : buf1;
        float* nxt = (slot == 0) ? buf1 : buf0;

        // A: wait until both neighbors have published field t halos
        if (tid == 0) {
            long g = 0;
            while (__hip_atomic_load(flags+up, __ATOMIC_ACQUIRE, __HIP_MEMORY_SCOPE_AGENT) < t)
                { __builtin_amdgcn_s_sleep(1); if (++g > 400000000L) break; }
        }
        if (tid == 64) {
            long g = 0;
            while (__hip_atomic_load(flags+dn, __ATOMIC_ACQUIRE, __HIP_MEMORY_SCOPE_AGENT) < t)
                { __builtin_amdgcn_s_sleep(1); if (++g > 400000000L) break; }
        }
        __syncthreads();

        // B: pull neighbor halo rows of field t into cur rows {0,1,47,48}
        for (int h = tid; h < 4*NXx; h += NTHREADS) {
            int rr = h / NXx, j = h - rr*NXx;
            float* srcp = (rr < 2) ? (upHalo + (slot*4 + 2 + rr)*NXx + j)
                                   : (dnHalo + (slot*4 + (rr-2))*NXx + j);
            float vv = __hip_atomic_load(srcp, __ATOMIC_RELAXED, __HIP_MEMORY_SCOPE_AGENT);
            int ldr = (rr < 2) ? rr : (45 + rr);   // 0,1,47,48
            cur[ldr*NXx + j] = vv;
        }
        __syncthreads();

        // C: compute field t+1 (in-place over field t-1, pointwise-safe)
        const float srcT = src[t];
        const float4* cur4 = (const float4*)cur;
        float4* nxt4 = (float4*)nxt;
        float* haloDst = myHalo + nslot*4*NXx;

#define DO_GROUP(KK, Ak, Kk) { \
        int gg = tid + KK*1024; \
        if (gg < GPB) { \
            int r = gg/NGrow, jg = gg - r*NGrow; \
            int R = r + 2; \
            int jgm = (jg==0) ? NGrow-1 : jg-1; \
            int jgp = (jg==NGrow-1) ? 0 : jg+1; \
            float4 Cv = cur4[R*NGrow+jg], Lv = cur4[R*NGrow+jgm], Rv = cur4[R*NGrow+jgp]; \
            float4 U1 = cur4[(R-1)*NGrow+jg], D1 = cur4[(R+1)*NGrow+jg]; \
            float4 U2 = cur4[(R-2)*NGrow+jg], D2 = cur4[(R+2)*NGrow+jg]; \
            float4 Pp = nxt4[R*NGrow+jg]; \
            float4 po; \
            { float lap = C2f*(U1.x+D1.x+Lv.w+Cv.y) + C3f*(U2.x+D2.x+Lv.z+Cv.z); \
              float t1v = 2.0f + 2.0f*(-2.5f)*Ak.x - Kk.x; float t0v = 1.0f - Kk.x; \
              po.x = Ak.x*lap + t1v*Cv.x - t0v*Pp.x; } \
            { float lap = C2f*(U1.y+D1.y+Cv.x+Cv.z) + C3f*(U2.y+D2.y+Lv.w+Cv.w); \
              float t1v = 2.0f + 2.0f*(-2.5f)*Ak.y - Kk.y; float t0v = 1.0f - Kk.y; \
              po.y = Ak.y*lap + t1v*Cv.y - t0v*Pp.y; } \
            { float lap = C2f*(U1.z+D1.z+Cv.y+Cv.w) + C3f*(U2.z+D2.z+Cv.x+Rv.x); \
              float t1v = 2.0f + 2.0f*(-2.5f)*Ak.z - Kk.z; float t0v = 1.0f - Kk.z; \
              po.z = Ak.z*lap + t1v*Cv.z - t0v*Pp.z; } \
            { float lap = C2f*(U1.w+D1.w+Cv.z+Rv.x) + C3f*(U2.w+D2.w+Cv.y+Rv.y); \
              float t1v = 2.0f + 2.0f*(-2.5f)*Ak.w - Kk.w; float t0v = 1.0f - Kk.w; \
              po.w = Ak.w*lap + t1v*Cv.w - t0v*Pp.w; } \
            if (gg == srcGG) { float add = betaV*srcT; \
                if (srcC==0) po.x += add; else if (srcC==1) po.y += add; \
                else if (srcC==2) po.z += add; else po.w += add; } \
            nxt4[R*NGrow+jg] = po; \
            if (r < 2 || r >= 43) { \
                int hrow = (r < 2) ? r : (r - 41); \
                float* hd = haloDst + hrow*NXx + jg*4; \
                __hip_atomic_store(hd+0, po.x, __ATOMIC_RELAXED, __HIP_MEMORY_SCOPE_AGENT); \
                __hip_atomic_store(hd+1, po.y, __ATOMIC_RELAXED, __HIP_MEMORY_SCOPE_AGENT); \
                __hip_atomic_store(hd+2, po.z, __ATOMIC_RELAXED, __HIP_MEMORY_SCOPE_AGENT); \
                __hip_atomic_store(hd+3, po.w, __ATOMIC_RELAXED, __HIP_MEMORY_SCOPE_AGENT); \
            } \
        } }

        DO_GROUP(0, A0, K0)
        DO_GROUP(1, A1, K1)
        DO_GROUP(2, A2, K2)
        DO_GROUP(3, A3, K3)
#undef DO_GROUP

        // D: all halo stores drained by the barrier's vmcnt(0); publish field t+1
        __syncthreads();
        if (tid == 0)
            __hip_atomic_store(flags+b, t+1, __ATOMIC_RELEASE, __HIP_MEMORY_SCOPE_AGENT);

        // E: receiver gather for step t (reads new field from LDS)
        if (mOwn) outP[(size_t)t*NMEASc] = nxt[mOff];
    }
}

extern "C" void kernel_launch(void* const* d_in, const int* in_sizes, int n_in,
                              void* d_out, int out_size, void* d_ws, size_t ws_size,
                              hipStream_t stream) {
    const float* v = (const float*)d_in[0];
    float* out = (float*)d_out;

    // workspace layout (floats)
    float* alpha  = (float*)d_ws;                 // 129600
    float* kap    = alpha + NXY;                  // 129600
    float* beta   = kap + NXY;                    // 32
    float* velmin = beta + NTRc;                  // 1
    float* src_d  = velmin + 1;                   // 640
    int*   meas_d = (int*)(src_d + NSTEPSc);      // 256
    int*   in_d   = meas_d + NMEASc;              // 32
    int*   flags  = in_d + NTRc;                  // 256
    float* haloG  = (float*)(flags + NBLK);       // 256*2*4*360

    static int   h_tab[NMEASc + NTRc];
    static float h_src[NSTEPSc];
    {
        const double step = 2.0*M_PI/256.0;
        for (int k = 0; k < NMEASc; ++k) {
            double th = (double)k * step;
            int ti0 = (int)floor(160.0*cos(th) + 179.5);
            int ti1 = (int)floor(160.0*sin(th) + 179.5);
            h_tab[k] = NXx*ti0 + ti1;
        }
        for (int r = 0; r < NTRc; ++r) h_tab[NMEASc + r] = h_tab[r*(NMEASc/NTRc)];
        for (int t = 0; t < NSTEPSc; ++t) {
            double tt = (double)t * 0.2;
            double d  = tt - 3.2;
            double e  = exp(-(d*d) / 288.0);
            double s  = sin(6.283185307179586 * tt);
            h_src[t] = (float)(e * s);
        }
    }
    hipMemcpyAsync(meas_d, h_tab, sizeof(int)*(NMEASc+NTRc), hipMemcpyHostToDevice, stream);
    hipMemcpyAsync(src_d, h_src, sizeof(float)*NSTEPSc, hipMemcpyHostToDevice, stream);
    // zero flags + halo buffers (field 0 halos must read as 0)
    hipMemsetAsync(flags, 0, sizeof(int)*NBLK + sizeof(float)*(size_t)NBLK*HALO_PER, stream);

    velmin_kernel<<<1, 256, 0, stream>>>(v, velmin);
    coef_kernel<<<(NXY+255)/256, 256, 0, stream>>>(v, velmin, alpha, kap);
    beta_kernel<<<1, 64, 0, stream>>>(v, in_d, beta);

    // allow >64KB dynamic LDS (141120 B)
    hipFuncSetAttribute((const void*)persist_kernel,
                        hipFuncAttributeMaxDynamicSharedMemorySize, LDSFLOATS*4);

    persist_kernel<<<NBLK, NTHREADS, LDSFLOATS*4, stream>>>(
        alpha, kap, beta, src_d, meas_d, in_d, flags, haloG, out);
}

// Round 5
// 7674.793 us; speedup vs baseline: 1.9929x; 1.0227x over previous
//
#include <hip/hip_runtime.h>
#include <math.h>

#ifndef M_PI
#define M_PI 3.14159265358979323846
#endif

#define NXx   360
#define NXY   (NXx*NXx)
#define NTRc  32
#define NMEASc 256
#define NSTEPSc 640
#define NBCc  15
#define PADc  73
#define NVc   214

#define BROWS 45
#define NBANDS 8
#define NBLK  (NTRc*NBANDS)     // 256 blocks == 256 CUs
#define NTHREADS 1024
#define NGrow (NXx/4)           // 90
#define GPB   (BROWS*NGrow)     // 4050
#define NEDGE (4*NGrow)         // 360 edge groups (rows 0,1,43,44)
#define LDSROWS 49
#define LDSFLOATS (2*LDSROWS*NXx)
#define HALO_PER (2*4*NXx)      // 2 slots x 4 rows x 360

#define C2f   1.3333334f
#define C3f  (-0.083333336f)
#define ADX2  0.11111111f
#define DT2f  0.04f
#define DTf   0.2f
#define DXf   0.6f

__global__ void velmin_kernel(const float* __restrict__ v, float* __restrict__ velmin) {
    __shared__ float s[256];
    float m = 1.5f;
    for (int i = threadIdx.x; i < NVc*NVc; i += 256) m = fminf(m, v[i]);
    s[threadIdx.x] = m;
    __syncthreads();
    for (int o = 128; o > 0; o >>= 1) {
        if (threadIdx.x < o) s[threadIdx.x] = fminf(s[threadIdx.x], s[threadIdx.x+o]);
        __syncthreads();
    }
    if (threadIdx.x == 0) *velmin = s[0];
}

__global__ void coef_kernel(const float* __restrict__ v, const float* __restrict__ velmin_p,
                            float* __restrict__ alpha, float* __restrict__ kap) {
    int idx = blockIdx.x*256 + threadIdx.x;
    if (idx >= NXY) return;
    int i = idx / NXx, j = idx - i*NXx;
    float vc = 1.5f;
    if (i >= PADc && i < PADc+NVc && j >= PADc && j < PADc+NVc)
        vc = v[(i-PADc)*NVc + (j-PADc)];
    float v2 = vc*vc;
    float al = v2 * ADX2;
    float velmin = *velmin_p;
    const float a = (float)((NBCc-1)*0.6);
    float ks = 3.0f*velmin*9.2103405f/(2.0f*a);
    float damp = 0.0f;
    int k = -1;
    if (j >= NXx-NBCc)      k = j-(NXx-NBCc);
    else if (j < NBCc)      k = NBCc-1-j;
    else if (i >= NXx-NBCc) k = i-(NXx-NBCc);
    else if (i < NBCc)      k = NBCc-1-i;
    if (k >= 0) { float r = (float)k*DXf/a; damp = ks*r*r; }
    alpha[idx] = al;
    kap[idx]   = damp*DTf;
}

__global__ void beta_kernel(const float* __restrict__ v, const int* __restrict__ in_inds,
                            float* __restrict__ beta) {
    int tr = threadIdx.x;
    if (tr >= NTRc) return;
    int idx = in_inds[tr];
    int i = idx / NXx, j = idx - i*NXx;
    float vc = 1.5f;
    if (i >= PADc && i < PADc+NVc && j >= PADc && j < PADc+NVc)
        vc = v[(i-PADc)*NVc + (j-PADc)];
    beta[tr] = DT2f*vc*vc;
}

// Persistent LDS-resident kernel, edge-first pipelined:
//   edges -> barrier -> RELEASE flag (wave0; wbl2 overlaps interior) ->
//   interior -> ACQUIRE spin (waves 0/1; inv kills stale halo lines) ->
//   barrier -> pull halos -> gather.
// RELEASE/ACQUIRE on the flag are load-bearing (R4 post-mortem): halo slots
// are reused every 2 steps; the acquire's L2-invalidate is what prevents
// stale rereads, the release's writeback publishes other waves' halo stores.
__global__ __launch_bounds__(NTHREADS, 4) void persist_kernel(
    const float* __restrict__ alpha, const float* __restrict__ kap,
    const float* __restrict__ beta, const float* __restrict__ src,
    const int* __restrict__ meas_inds, const int* __restrict__ in_inds,
    int* flags, float* haloG, float* __restrict__ out)
{
    extern __shared__ float lds[];
    const int tid  = threadIdx.x;
    const int b    = blockIdx.x;
    const int tr   = b >> 3, band = b & 7;
    const int band0 = band*BROWS;
    const int up = (tr<<3) | ((band+7)&7);
    const int dn = (tr<<3) | ((band+1)&7);

    float* buf0 = lds;
    float* buf1 = lds + LDSROWS*NXx;

    for (int i = tid; i < LDSFLOATS; i += NTHREADS) lds[i] = 0.0f;

    const float betaV = beta[tr];
    const int sCell = in_inds[tr];
    const int sr = sCell/NXx, sc = sCell - sr*NXx;

    // per-slot loop-invariant precompute; slot 0 puts the 360 edge groups
    // (rows 0,1,43,44) at tid<NEDGE so they compute first each step.
    int c0=-1,l0=0,r0=0,q0=-1; float4 A0=make_float4(0,0,0,0), K0=A0;
    int c1=-1,l1=0,r1=0,q1=-1; float4 A1=A0, K1=A0;
    int c2=-1,l2=0,r2=0,q2=-1; float4 A2=A0, K2=A0;
    int c3=-1,l3=0,r3=0,q3=-1; float4 A3=A0, K3=A0;
    int h0 = 0;

#define INIT_SLOT(KK, Ck,Lk,Rk,Qk,AAk,KKk) { \
    int gg = tid + KK*1024; \
    if (gg < GPB) { \
        int rloc, jg; \
        if (gg < NEDGE) { int kk = gg/NGrow; jg = gg - kk*NGrow; rloc = (kk<2)?kk:(41+kk); } \
        else { int ii = gg - NEDGE; rloc = 2 + ii/NGrow; jg = ii - (ii/NGrow)*NGrow; } \
        Ck = (rloc+2)*NGrow + jg; \
        Lk = Ck + ((jg==0)?NGrow-1:-1); \
        Rk = Ck + ((jg==NGrow-1)?-(NGrow-1):1); \
        int gr = band0 + rloc, gi = gr*NXx + jg*4; \
        AAk = *(const float4*)(alpha+gi); KKk = *(const float4*)(kap+gi); \
        Qk = (gr==sr && (sc>>2)==jg) ? (sc&3) : -1; \
    } }

    INIT_SLOT(0, c0,l0,r0,q0,A0,K0)
    INIT_SLOT(1, c1,l1,r1,q1,A1,K1)
    INIT_SLOT(2, c2,l2,r2,q2,A2,K2)
    INIT_SLOT(3, c3,l3,r3,q3,A3,K3)
#undef INIT_SLOT
    if (tid < NEDGE) {
        int kk = tid/NGrow, jg = tid - kk*NGrow;
        int rloc = (kk<2)?kk:(41+kk);
        int hrow = (rloc<2)? rloc : (rloc-41);   // 0,1,2,3
        h0 = hrow*NXx + jg*4;
    }

    bool mOwn = false; int mOff = 0;
    float* outP = out + ((size_t)tr*NSTEPSc)*NMEASc + tid;
    if (tid < NMEASc) {
        int mi = meas_inds[tid]; int row = mi/NXx, col = mi - row*NXx;
        if (row >= band0 && row < band0+BROWS) { mOwn = true; mOff = (row-band0+2)*NXx + col; }
    }

    float* myHalo = haloG + (size_t)b*HALO_PER;
    float* upHalo = haloG + (size_t)up*HALO_PER;
    float* dnHalo = haloG + (size_t)dn*HALO_PER;

    __syncthreads();

#define COMPUTE_PO(Ck,Lk,Rk,Qk,AAk,KKk) \
    float4 Cv = cur4[Ck], Lv = cur4[Lk], Rv = cur4[Rk]; \
    float4 U1 = cur4[Ck-NGrow], D1 = cur4[Ck+NGrow]; \
    float4 U2 = cur4[Ck-2*NGrow], D2 = cur4[Ck+2*NGrow]; \
    float4 Pp = nxt4[Ck]; float4 po; \
    { float lap = C2f*(U1.x+D1.x+Lv.w+Cv.y) + C3f*(U2.x+D2.x+Lv.z+Cv.z); \
      float t1v = 2.0f + 2.0f*(-2.5f)*AAk.x - KKk.x; float t0v = 1.0f - KKk.x; \
      po.x = AAk.x*lap + t1v*Cv.x - t0v*Pp.x; } \
    { float lap = C2f*(U1.y+D1.y+Cv.x+Cv.z) + C3f*(U2.y+D2.y+Lv.w+Cv.w); \
      float t1v = 2.0f + 2.0f*(-2.5f)*AAk.y - KKk.y; float t0v = 1.0f - KKk.y; \
      po.y = AAk.y*lap + t1v*Cv.y - t0v*Pp.y; } \
    { float lap = C2f*(U1.z+D1.z+Cv.y+Cv.w) + C3f*(U2.z+D2.z+Cv.x+Rv.x); \
      float t1v = 2.0f + 2.0f*(-2.5f)*AAk.z - KKk.z; float t0v = 1.0f - KKk.z; \
      po.z = AAk.z*lap + t1v*Cv.z - t0v*Pp.z; } \
    { float lap = C2f*(U1.w+D1.w+Cv.z+Rv.x) + C3f*(U2.w+D2.w+Cv.y+Rv.y); \
      float t1v = 2.0f + 2.0f*(-2.5f)*AAk.w - KKk.w; float t0v = 1.0f - KKk.w; \
      po.w = AAk.w*lap + t1v*Cv.w - t0v*Pp.w; } \
    if (Qk >= 0) { float add = betaV*srcT; \
        if (Qk==0) po.x += add; else if (Qk==1) po.y += add; \
        else if (Qk==2) po.z += add; else po.w += add; } \
    nxt4[Ck] = po;

    for (int t = 0; t < NSTEPSc; ++t) {
        const int slot = t & 1, nslot = slot ^ 1;
        float* cur = (slot == 0) ? buf0 : buf1;
        float* nxt = (slot == 0) ? buf1 : buf0;
        const float4* cur4 = (const float4*)cur;
        float4* nxt4 = (float4*)nxt;
        const float srcT = src[t];

        // ---- phase 1: edge rows (0,1,43,44) + halo publish ----
        if (tid < NEDGE) {
            COMPUTE_PO(c0,l0,r0,q0,A0,K0)
            float* hd = myHalo + nslot*4*NXx + h0;
            __hip_atomic_store(hd+0, po.x, __ATOMIC_RELAXED, __HIP_MEMORY_SCOPE_AGENT);
            __hip_atomic_store(hd+1, po.y, __ATOMIC_RELAXED, __HIP_MEMORY_SCOPE_AGENT);
            __hip_atomic_store(hd+2, po.z, __ATOMIC_RELAXED, __HIP_MEMORY_SCOPE_AGENT);
            __hip_atomic_store(hd+3, po.w, __ATOMIC_RELAXED, __HIP_MEMORY_SCOPE_AGENT);
        }
        __syncthreads();   // all waves' halo stores drained (vmcnt 0)
        if (tid == 0)      // RELEASE: waitcnt + L2 writeback, wave0 only;
                           // overlaps other waves' interior compute
            __hip_atomic_store(flags+b, t+1, __ATOMIC_RELEASE, __HIP_MEMORY_SCOPE_AGENT);

        // ---- phase 2: interior rows (2..42) — hides publish/flag latency ----
        if (tid >= NEDGE) { COMPUTE_PO(c0,l0,r0,q0,A0,K0) }
        { COMPUTE_PO(c1,l1,r1,q1,A1,K1) }
        { COMPUTE_PO(c2,l2,r2,q2,A2,K2) }
        if (c3 >= 0) { COMPUTE_PO(c3,l3,r3,q3,A3,K3) }

        // ---- phase 3: wait for neighbors' field t+1 halos (ACQUIRE: inv) ----
        if (tid == 0) {
            int g = 0;
            while (__hip_atomic_load(flags+up, __ATOMIC_ACQUIRE, __HIP_MEMORY_SCOPE_AGENT) <= t)
                { if (++g > 2000000) break; }
        }
        if (tid == 64) {
            int g = 0;
            while (__hip_atomic_load(flags+dn, __ATOMIC_ACQUIRE, __HIP_MEMORY_SCOPE_AGENT) <= t)
                { if (++g > 2000000) break; }
        }
        __syncthreads();

        // ---- phase 4: pull halos of field t+1 into nxt rows {0,1,47,48} ----
        for (int h = tid; h < 4*NXx; h += NTHREADS) {
            int rr = h / NXx, j = h - rr*NXx;
            float* sp = (rr < 2) ? (upHalo + (nslot*4 + 2 + rr)*NXx + j)
                                 : (dnHalo + (nslot*4 + (rr-2))*NXx + j);
            float vv = __hip_atomic_load(sp, __ATOMIC_RELAXED, __HIP_MEMORY_SCOPE_AGENT);
            int ldr = (rr < 2) ? rr : (45 + rr);
            nxt[ldr*NXx + j] = vv;
        }

        // ---- phase 5: receiver gather for step t (field t+1, from LDS) ----
        if (mOwn) outP[(size_t)t*NMEASc] = nxt[mOff];

        __syncthreads();
    }
#undef COMPUTE_PO
}

extern "C" void kernel_launch(void* const* d_in, const int* in_sizes, int n_in,
                              void* d_out, int out_size, void* d_ws, size_t ws_size,
                              hipStream_t stream) {
    const float* v = (const float*)d_in[0];
    float* out = (float*)d_out;

    float* alpha  = (float*)d_ws;                 // 129600
    float* kap    = alpha + NXY;                  // 129600
    float* beta   = kap + NXY;                    // 32
    float* velmin = beta + NTRc;                  // 1
    float* src_d  = velmin + 1;                   // 640
    int*   meas_d = (int*)(src_d + NSTEPSc);      // 256
    int*   in_d   = meas_d + NMEASc;              // 32
    int*   flags  = in_d + NTRc;                  // 256
    float* haloG  = (float*)(flags + NBLK);       // 256*2880

    static int   h_tab[NMEASc + NTRc];
    static float h_src[NSTEPSc];
    {
        const double step = 2.0*M_PI/256.0;
        for (int k = 0; k < NMEASc; ++k) {
            double th = (double)k * step;
            int ti0 = (int)floor(160.0*cos(th) + 179.5);
            int ti1 = (int)floor(160.0*sin(th) + 179.5);
            h_tab[k] = NXx*ti0 + ti1;
        }
        for (int r = 0; r < NTRc; ++r) h_tab[NMEASc + r] = h_tab[r*(NMEASc/NTRc)];
        for (int t = 0; t < NSTEPSc; ++t) {
            double tt = (double)t * 0.2;
            double d  = tt - 3.2;
            double e  = exp(-(d*d) / 288.0);
            double s  = sin(6.283185307179586 * tt);
            h_src[t] = (float)(e * s);
        }
    }
    hipMemcpyAsync(meas_d, h_tab, sizeof(int)*(NMEASc+NTRc), hipMemcpyHostToDevice, stream);
    hipMemcpyAsync(src_d, h_src, sizeof(float)*NSTEPSc, hipMemcpyHostToDevice, stream);
    hipMemsetAsync(flags, 0, sizeof(int)*NBLK, stream);   // flags must start at 0

    velmin_kernel<<<1, 256, 0, stream>>>(v, velmin);
    coef_kernel<<<(NXY+255)/256, 256, 0, stream>>>(v, velmin, alpha, kap);
    beta_kernel<<<1, 64, 0, stream>>>(v, in_d, beta);

    hipFuncSetAttribute((const void*)persist_kernel,
                        hipFuncAttributeMaxDynamicSharedMemorySize, LDSFLOATS*4);

    persist_kernel<<<NBLK, NTHREADS, LDSFLOATS*4, stream>>>(
        alpha, kap, beta, src_d, meas_d, in_d, flags, haloG, out);
}

// Round 7
// 2250.319 us; speedup vs baseline: 6.7969x; 3.4105x over previous
//
#include <hip/hip_runtime.h>
#include <math.h>

#ifndef M_PI
#define M_PI 3.14159265358979323846
#endif

#define NXx   360
#define NXY   (NXx*NXx)
#define NTRc  32
#define NMEASc 256
#define NSTEPSc 640
#define NBCc  15
#define PADc  73
#define NVc   214

#define BROWS 45
#define NBANDS 8
#define NBLK  (NTRc*NBANDS)     // 256 blocks == 256 CUs
#define NTHREADS 1024
#define NGrow (NXx/4)           // 90
#define GPB   (BROWS*NGrow)     // 4050
#define NEDGE (4*NGrow)         // 360 edge groups (rows 0,1,43,44)
#define LDSROWS 49
#define LDSFLOATS (2*LDSROWS*NXx)
#define NSLOT 4
#define HALO_PER (NSLOT*4*NXx)  // 4 slots x 4 rows x 360

#define C2f   1.3333334f
#define C3f  (-0.083333336f)
#define ADX2  0.11111111f
#define DT2f  0.04f
#define DTf   0.2f
#define DXf   0.6f

// native vector type for inline-asm "v" constraints (HIP float4 is a struct)
typedef float f32x4 __attribute__((ext_vector_type(4)));

// ---- system-coherent (sc0 sc1) transport: executes at chip coherence point,
// bypasses L1/L2 on both sides -> no buffer_wbl2 / buffer_inv fences needed.
__device__ __forceinline__ void store4_sys(float* p, float4 v) {
    f32x4 vv; vv.x = v.x; vv.y = v.y; vv.z = v.z; vv.w = v.w;
    asm volatile("global_store_dwordx4 %0, %1, off sc0 sc1" :: "v"(p), "v"(vv) : "memory");
}
__device__ __forceinline__ float4 load4_sys(const float* p) {
    f32x4 r;
    asm volatile("global_load_dwordx4 %0, %1, off sc0 sc1\n\ts_waitcnt vmcnt(0)"
                 : "=&v"(r) : "v"(p) : "memory");
    return make_float4(r.x, r.y, r.z, r.w);
}
__device__ __forceinline__ void storei_sys(int* p, int v) {
    asm volatile("global_store_dword %0, %1, off sc0 sc1" :: "v"(p), "v"(v) : "memory");
}
__device__ __forceinline__ int loadi_sys(const int* p) {
    int r;
    asm volatile("global_load_dword %0, %1, off sc0 sc1\n\ts_waitcnt vmcnt(0)"
                 : "=&v"(r) : "v"(p) : "memory");
    return r;
}
__device__ __forceinline__ void drain_vm() {
    asm volatile("s_waitcnt vmcnt(0)" ::: "memory");
}

__global__ void velmin_kernel(const float* __restrict__ v, float* __restrict__ velmin) {
    __shared__ float s[256];
    float m = 1.5f;
    for (int i = threadIdx.x; i < NVc*NVc; i += 256) m = fminf(m, v[i]);
    s[threadIdx.x] = m;
    __syncthreads();
    for (int o = 128; o > 0; o >>= 1) {
        if (threadIdx.x < o) s[threadIdx.x] = fminf(s[threadIdx.x], s[threadIdx.x+o]);
        __syncthreads();
    }
    if (threadIdx.x == 0) *velmin = s[0];
}

__global__ void coef_kernel(const float* __restrict__ v, const float* __restrict__ velmin_p,
                            float* __restrict__ alpha, float* __restrict__ kap) {
    int idx = blockIdx.x*256 + threadIdx.x;
    if (idx >= NXY) return;
    int i = idx / NXx, j = idx - i*NXx;
    float vc = 1.5f;
    if (i >= PADc && i < PADc+NVc && j >= PADc && j < PADc+NVc)
        vc = v[(i-PADc)*NVc + (j-PADc)];
    float v2 = vc*vc;
    float al = v2 * ADX2;
    float velmin = *velmin_p;
    const float a = (float)((NBCc-1)*0.6);
    float ks = 3.0f*velmin*9.2103405f/(2.0f*a);
    float damp = 0.0f;
    int k = -1;
    if (j >= NXx-NBCc)      k = j-(NXx-NBCc);
    else if (j < NBCc)      k = NBCc-1-j;
    else if (i >= NXx-NBCc) k = i-(NXx-NBCc);
    else if (i < NBCc)      k = NBCc-1-i;
    if (k >= 0) { float r = (float)k*DXf/a; damp = ks*r*r; }
    alpha[idx] = al;
    kap[idx]   = damp*DTf;
}

__global__ void beta_kernel(const float* __restrict__ v, const int* __restrict__ in_inds,
                            float* __restrict__ beta) {
    int tr = threadIdx.x;
    if (tr >= NTRc) return;
    int idx = in_inds[tr];
    int i = idx / NXx, j = idx - i*NXx;
    float vc = 1.5f;
    if (i >= PADc && i < PADc+NVc && j >= PADc && j < PADc+NVc)
        vc = v[(i-PADc)*NVc + (j-PADc)];
    beta[tr] = DT2f*vc*vc;
}

// Persistent LDS-resident kernel. Fence-free neighbor exchange:
//  - halo/flag data moves via sc0sc1 (system-coherent) ops, no wbl2/inv.
//  - 4 halo slots (slot = field & 3): writer reuses a slot only when >= 3
//    steps past the reader's gated position (max drift 1) -> race-free.
//  - edge-first: edges -> drain -> barrier -> flag publish -> interior ->
//    poll -> barrier -> pull next halos -> gather.
__global__ __launch_bounds__(NTHREADS, 4) void persist_kernel(
    const float* __restrict__ alpha, const float* __restrict__ kap,
    const float* __restrict__ beta, const float* __restrict__ src,
    const int* __restrict__ meas_inds, const int* __restrict__ in_inds,
    int* flags, float* haloG, float* __restrict__ out)
{
    extern __shared__ float lds[];
    const int tid  = threadIdx.x;
    const int b    = blockIdx.x;
    const int tr   = b >> 3, band = b & 7;
    const int band0 = band*BROWS;
    const int up = (tr<<3) | ((band+7)&7);
    const int dn = (tr<<3) | ((band+1)&7);

    float* buf0 = lds;
    float* buf1 = lds + LDSROWS*NXx;

    for (int i = tid; i < LDSFLOATS; i += NTHREADS) lds[i] = 0.0f;

    const float betaV = beta[tr];
    const int sCell = in_inds[tr];
    const int sr = sCell/NXx, sc = sCell - sr*NXx;

    int c0=-1,l0=0,r0=0,q0=-1; float4 A0=make_float4(0,0,0,0), K0=A0;
    int c1=-1,l1=0,r1=0,q1=-1; float4 A1=A0, K1=A0;
    int c2=-1,l2=0,r2=0,q2=-1; float4 A2=A0, K2=A0;
    int c3=-1,l3=0,r3=0,q3=-1; float4 A3=A0, K3=A0;
    int h0 = 0;

#define INIT_SLOT(KK, Ck,Lk,Rk,Qk,AAk,KKk) { \
    int gg = tid + KK*1024; \
    if (gg < GPB) { \
        int rloc, jg; \
        if (gg < NEDGE) { int kk = gg/NGrow; jg = gg - kk*NGrow; rloc = (kk<2)?kk:(41+kk); } \
        else { int ii = gg - NEDGE; rloc = 2 + ii/NGrow; jg = ii - (ii/NGrow)*NGrow; } \
        Ck = (rloc+2)*NGrow + jg; \
        Lk = Ck + ((jg==0)?NGrow-1:-1); \
        Rk = Ck + ((jg==NGrow-1)?-(NGrow-1):1); \
        int gr = band0 + rloc, gi = gr*NXx + jg*4; \
        AAk = *(const float4*)(alpha+gi); KKk = *(const float4*)(kap+gi); \
        Qk = (gr==sr && (sc>>2)==jg) ? (sc&3) : -1; \
    } }

    INIT_SLOT(0, c0,l0,r0,q0,A0,K0)
    INIT_SLOT(1, c1,l1,r1,q1,A1,K1)
    INIT_SLOT(2, c2,l2,r2,q2,A2,K2)
    INIT_SLOT(3, c3,l3,r3,q3,A3,K3)
#undef INIT_SLOT
    if (tid < NEDGE) {
        int kk = tid/NGrow, jg = tid - kk*NGrow;
        int rloc = (kk<2)?kk:(41+kk);
        int hrow = (rloc<2)? rloc : (rloc-41);   // 0,1,2,3
        h0 = hrow*NXx + jg*4;
    }

    bool mOwn = false; int mOff = 0;
    float* outP = out + ((size_t)tr*NSTEPSc)*NMEASc + tid;
    if (tid < NMEASc) {
        int mi = meas_inds[tid]; int row = mi/NXx, col = mi - row*NXx;
        if (row >= band0 && row < band0+BROWS) { mOwn = true; mOff = (row-band0+2)*NXx + col; }
    }

    float* myHalo = haloG + (size_t)b*HALO_PER;
    float* upHalo = haloG + (size_t)up*HALO_PER;
    float* dnHalo = haloG + (size_t)dn*HALO_PER;

    __syncthreads();

#define COMPUTE_PO(Ck,Lk,Rk,Qk,AAk,KKk) \
    float4 Cv = cur4[Ck], Lv = cur4[Lk], Rv = cur4[Rk]; \
    float4 U1 = cur4[Ck-NGrow], D1 = cur4[Ck+NGrow]; \
    float4 U2 = cur4[Ck-2*NGrow], D2 = cur4[Ck+2*NGrow]; \
    float4 Pp = nxt4[Ck]; float4 po; \
    { float lap = C2f*(U1.x+D1.x+Lv.w+Cv.y) + C3f*(U2.x+D2.x+Lv.z+Cv.z); \
      float t1v = 2.0f + 2.0f*(-2.5f)*AAk.x - KKk.x; float t0v = 1.0f - KKk.x; \
      po.x = AAk.x*lap + t1v*Cv.x - t0v*Pp.x; } \
    { float lap = C2f*(U1.y+D1.y+Cv.x+Cv.z) + C3f*(U2.y+D2.y+Lv.w+Cv.w); \
      float t1v = 2.0f + 2.0f*(-2.5f)*AAk.y - KKk.y; float t0v = 1.0f - KKk.y; \
      po.y = AAk.y*lap + t1v*Cv.y - t0v*Pp.y; } \
    { float lap = C2f*(U1.z+D1.z+Cv.y+Cv.w) + C3f*(U2.z+D2.z+Cv.x+Rv.x); \
      float t1v = 2.0f + 2.0f*(-2.5f)*AAk.z - KKk.z; float t0v = 1.0f - KKk.z; \
      po.z = AAk.z*lap + t1v*Cv.z - t0v*Pp.z; } \
    { float lap = C2f*(U1.w+D1.w+Cv.z+Rv.x) + C3f*(U2.w+D2.w+Cv.y+Rv.y); \
      float t1v = 2.0f + 2.0f*(-2.5f)*AAk.w - KKk.w; float t0v = 1.0f - KKk.w; \
      po.w = AAk.w*lap + t1v*Cv.w - t0v*Pp.w; } \
    if (Qk >= 0) { float add = betaV*srcT; \
        if (Qk==0) po.x += add; else if (Qk==1) po.y += add; \
        else if (Qk==2) po.z += add; else po.w += add; } \
    nxt4[Ck] = po;

    for (int t = 0; t < NSTEPSc; ++t) {
        const int slot = t & 1;
        const int hs   = (t+1) & 3;     // halo slot for field t+1
        float* cur = (slot == 0) ? buf0 : buf1;
        float* nxt = (slot == 0) ? buf1 : buf0;
        const float4* cur4 = (const float4*)cur;
        float4* nxt4 = (float4*)nxt;
        const float srcT = src[t];

        // ---- phase 1: edge rows (0,1,43,44); publish halo(t+1) sc0sc1 ----
        if (tid < NEDGE) {
            COMPUTE_PO(c0,l0,r0,q0,A0,K0)
            store4_sys(myHalo + hs*4*NXx + h0, po);
            drain_vm();   // halo store acked at coherence point before barrier
        }
        __syncthreads();
        if (tid == 0) storei_sys(flags + b, t + 1);

        // ---- phase 2: interior rows (2..42) — overlaps flag propagation ----
        if (tid >= NEDGE) { COMPUTE_PO(c0,l0,r0,q0,A0,K0) }
        { COMPUTE_PO(c1,l1,r1,q1,A1,K1) }
        { COMPUTE_PO(c2,l2,r2,q2,A2,K2) }
        if (c3 >= 0) { COMPUTE_PO(c3,l3,r3,q3,A3,K3) }

        // ---- phase 3: wait for neighbors' field t+1 (sc0sc1 polls, no inv) ----
        if (tid == 0) {
            int g = 0;
            while (loadi_sys(flags + up) <= t)
                { __builtin_amdgcn_s_sleep(1); if (++g > 200000) break; }
        }
        if (tid == 64) {
            int g = 0;
            while (loadi_sys(flags + dn) <= t)
                { __builtin_amdgcn_s_sleep(1); if (++g > 200000) break; }
        }
        __syncthreads();

        // ---- phase 4: pull halos of field t+1 into nxt rows {0,1,47,48} ----
        if (tid < 4*NGrow) {
            int rr = tid / NGrow, jg = tid - rr*NGrow;
            const float* sp = (rr < 2) ? (upHalo + (hs*4 + 2 + rr)*NXx + jg*4)
                                       : (dnHalo + (hs*4 + (rr-2))*NXx + jg*4);
            float4 hv = load4_sys(sp);
            int ldr = (rr < 2) ? rr : (45 + rr);    // 0,1,47,48
            *(float4*)(nxt + ldr*NXx + jg*4) = hv;
        }

        // ---- phase 5: receiver gather for step t (field t+1, from LDS) ----
        if (mOwn) outP[(size_t)t*NMEASc] = nxt[mOff];

        __syncthreads();
    }
#undef COMPUTE_PO
}

extern "C" void kernel_launch(void* const* d_in, const int* in_sizes, int n_in,
                              void* d_out, int out_size, void* d_ws, size_t ws_size,
                              hipStream_t stream) {
    const float* v = (const float*)d_in[0];
    float* out = (float*)d_out;

    // workspace layout: haloG first (16B-aligned for dwordx4)
    float* haloG  = (float*)d_ws;                       // NBLK*HALO_PER
    float* alpha  = haloG + (size_t)NBLK*HALO_PER;      // 129600
    float* kap    = alpha + NXY;                        // 129600
    float* beta   = kap + NXY;                          // 32
    float* velmin = beta + NTRc;                        // 1
    float* src_d  = velmin + 1;                         // 640
    int*   meas_d = (int*)(src_d + NSTEPSc);            // 256
    int*   in_d   = meas_d + NMEASc;                    // 32
    int*   flags  = in_d + NTRc;                        // 256

    static int   h_tab[NMEASc + NTRc];
    static float h_src[NSTEPSc];
    {
        const double step = 2.0*M_PI/256.0;
        for (int k = 0; k < NMEASc; ++k) {
            double th = (double)k * step;
            int ti0 = (int)floor(160.0*cos(th) + 179.5);
            int ti1 = (int)floor(160.0*sin(th) + 179.5);
            h_tab[k] = NXx*ti0 + ti1;
        }
        for (int r = 0; r < NTRc; ++r) h_tab[NMEASc + r] = h_tab[r*(NMEASc/NTRc)];
        for (int t = 0; t < NSTEPSc; ++t) {
            double tt = (double)t * 0.2;
            double d  = tt - 3.2;
            double e  = exp(-(d*d) / 288.0);
            double s  = sin(6.283185307179586 * tt);
            h_src[t] = (float)(e * s);
        }
    }
    (void)hipMemcpyAsync(meas_d, h_tab, sizeof(int)*(NMEASc+NTRc), hipMemcpyHostToDevice, stream);
    (void)hipMemcpyAsync(src_d, h_src, sizeof(float)*NSTEPSc, hipMemcpyHostToDevice, stream);
    // zero flags + halo slots
    (void)hipMemsetAsync(haloG, 0, sizeof(float)*(size_t)NBLK*HALO_PER, stream);
    (void)hipMemsetAsync(flags, 0, sizeof(int)*NBLK, stream);

    velmin_kernel<<<1, 256, 0, stream>>>(v, velmin);
    coef_kernel<<<(NXY+255)/256, 256, 0, stream>>>(v, velmin, alpha, kap);
    beta_kernel<<<1, 64, 0, stream>>>(v, in_d, beta);

    (void)hipFuncSetAttribute((const void*)persist_kernel,
                        hipFuncAttributeMaxDynamicSharedMemorySize, LDSFLOATS*4);

    persist_kernel<<<NBLK, NTHREADS, LDSFLOATS*4, stream>>>(
        alpha, kap, beta, src_d, meas_d, in_d, flags, haloG, out);
}